// Round 1
// baseline (348.545 us; speedup 1.0000x reference)
//
#include <hip/hip_runtime.h>
#include <hip/hip_bf16.h>

#define B_   2
#define S_   2048
#define HID_ 2048
#define H_   16
#define KVH_ 4
#define D_   128
#define M_   4096
#define NQKV 3072

typedef __attribute__((ext_vector_type(8))) short bf16x8;    // 8 bf16 = 4 VGPR
typedef __attribute__((ext_vector_type(4))) float f32x4;
typedef __attribute__((ext_vector_type(16))) float f32x16;
typedef const __attribute__((address_space(1))) unsigned int* gas_p;
typedef __attribute__((address_space(3))) unsigned int* las_p;

__device__ __forceinline__ unsigned short f2b(float f) {
    __hip_bfloat16 h = __float2bfloat16(f);
    return *reinterpret_cast<unsigned short*>(&h);
}
__device__ __forceinline__ float b2f(unsigned short u) {
    __hip_bfloat16 h;
    *reinterpret_cast<unsigned short*>(&h) = u;
    return __bfloat162float(h);
}

// ---------- convert x: fp32 -> bf16 ----------------------------------------
__global__ __launch_bounds__(256)
void convert_x(const float* __restrict__ x, unsigned short* __restrict__ xb) {
    int i = (blockIdx.x * 256 + threadIdx.x) * 4;
    float4 v = *(const float4*)(x + i);
    ushort4 o;
    o.x = f2b(v.x); o.y = f2b(v.y); o.z = f2b(v.z); o.w = f2b(v.w);
    *(ushort4*)(xb + i) = o;
}

// ---------- all four weight converts in one launch (z selects matrix) ------
__global__ __launch_bounds__(256)
void convert_w_all(const float* __restrict__ wq, const float* __restrict__ wk,
                   const float* __restrict__ wv, const float* __restrict__ wo,
                   unsigned short* __restrict__ wqkvT,
                   unsigned short* __restrict__ woT) {
    __shared__ float tile[32][33];
    int z = blockIdx.z;
    const float* w; int N, nbase; unsigned short* dst;
    if (z == 0)      { w = wq; N = 2048; nbase = 0;    dst = wqkvT; }
    else if (z == 1) { w = wk; N = 512;  nbase = 2048; dst = wqkvT; }
    else if (z == 2) { w = wv; N = 512;  nbase = 2560; dst = wqkvT; }
    else             { w = wo; N = 2048; nbase = 0;    dst = woT; }
    int n0 = blockIdx.x * 32, k0 = blockIdx.y * 32;
    if (n0 >= N) return;
    int tx = threadIdx.x & 31, ty = threadIdx.x >> 5;
    #pragma unroll
    for (int j = 0; j < 4; j++)
        tile[ty + j*8][tx] = w[(size_t)(k0 + ty + j*8) * N + n0 + tx];
    __syncthreads();
    #pragma unroll
    for (int j = 0; j < 4; j++)
        dst[(size_t)(nbase + n0 + ty + j*8) * 2048 + k0 + tx] = f2b(tile[tx][ty + j*8]);
}

// ---------- 8-phase 256x256 GEMM (T2+T3+T4+T5), shared by QKV & OUT --------
// 512 thr = 8 waves (2M x 4N), per-wave 128x64 C, 16x16x32 MFMA.
// LDS 128KB: As/Bs[2 bufs][256 rows][64 k], XOR-swizzled (slot = chunk^(row&7))
//   staged by global_load_lds w=16 with inverse-swizzled global src (rule 21).
// Schedule (derived; lands on template's vmcnt(6) / 3-half-tiles-in-flight):
//   wave rows: mi*128 + wr*64 + f*16   wave cols: ni*128 + wc*32 + g*16
//   ph0 (m0,n0): rd A-half0(8) + B-half0(4); stage A1(t+1)->buf1
//   ph1 (m0,n1): rd B-half1(4);              stage A0(t+2)->buf0
//   ph2 (m1,n0): rd A-half1(8);              stage B0(t+2)->buf0
//   ph3 (m1,n1): (regs);                     stage B1(t+2)->buf0  GATE vmcnt(6)
//   ph4..7: same on buf1 (tile t+1), staging A1(t+2),A0/B0/B1(t+3), GATE vmcnt(6)
// Every stage targets a region whose last ds_read drained (lgkmcnt(0) before
// MFMA) a barrier earlier; every first read of new data is behind a vmcnt gate
// + barrier covering all 4 halves of that tile.  Raw s_barrier (no vmcnt(0)
// drain) keeps 3 half-tiles of global_load_lds in flight across barriers.
#define BAR    asm volatile("s_barrier" ::: "memory")
#define LG0    do { asm volatile("s_waitcnt lgkmcnt(0)" ::: "memory"); \
                    __builtin_amdgcn_sched_barrier(0); } while (0)
#define GATE6  asm volatile("s_waitcnt vmcnt(6)" ::: "memory")
#define GATE0  asm volatile("s_waitcnt vmcnt(0)" ::: "memory")
#define PHI    __builtin_amdgcn_s_setprio(1)
#define PLO    __builtin_amdgcn_s_setprio(0)

#define STG(srcrow, ldsbase, half, tile) do {                                   \
    _Pragma("unroll")                                                           \
    for (int it_ = 0; it_ < 2; ++it_) {                                         \
      int p_ = w * 128 + it_ * 64 + lane;                                       \
      int r_ = (half) * 128 + (p_ >> 3);                                        \
      int q8_ = ((p_ & 7) ^ ((p_ >> 3) & 7)) * 8;                               \
      __builtin_amdgcn_global_load_lds(                                         \
          (gas_p)((srcrow) + (size_t)r_ * 2048 + (tile) * 64 + q8_),            \
          (las_p)((char*)(ldsbase) + ((half) * 1024 + w * 128 + it_ * 64) * 16),\
          16, 0, 0);                                                            \
    } } while (0)

#define RD_AF(bufi, mi) do {                                                    \
    const unsigned short* Ab_ = &As[bufi][0] + (mi) * 8192 + wr * 4096 + l15 * 64; \
    _Pragma("unroll")                                                           \
    for (int f_ = 0; f_ < 4; ++f_) {                                            \
      af[f_][0] = *(const bf16x8*)(Ab_ + f_ * 1024 + slot0);                    \
      af[f_][1] = *(const bf16x8*)(Ab_ + f_ * 1024 + slot1);                    \
    } } while (0)

#define RD_BF(bufi, ni) do {                                                    \
    const unsigned short* Bb_ = &Bs[bufi][0] + (ni) * 8192 + wc * 2048 + l15 * 64; \
    _Pragma("unroll")                                                           \
    for (int g_ = 0; g_ < 2; ++g_) {                                            \
      bfr[ni][g_][0] = *(const bf16x8*)(Bb_ + g_ * 1024 + slot0);               \
      bfr[ni][g_][1] = *(const bf16x8*)(Bb_ + g_ * 1024 + slot1);               \
    } } while (0)

#define MM(mi, ni) do {                                                         \
    _Pragma("unroll")                                                           \
    for (int f_ = 0; f_ < 4; ++f_)                                              \
      _Pragma("unroll")                                                         \
      for (int g_ = 0; g_ < 2; ++g_) {                                          \
        acc[(mi)*4 + f_][(ni)*2 + g_] = __builtin_amdgcn_mfma_f32_16x16x32_bf16(\
            af[f_][0], bfr[ni][g_][0], acc[(mi)*4 + f_][(ni)*2 + g_], 0, 0, 0); \
        acc[(mi)*4 + f_][(ni)*2 + g_] = __builtin_amdgcn_mfma_f32_16x16x32_bf16(\
            af[f_][1], bfr[ni][g_][1], acc[(mi)*4 + f_][(ni)*2 + g_], 0, 0, 0); \
      } } while (0)

__global__ __launch_bounds__(512)
void gemm8(const unsigned short* __restrict__ A,
           const unsigned short* __restrict__ BT,
           int mode,                               // 0 = qkv (rope+vT), 1 = out (f32)
           unsigned short* __restrict__ qkvb,
           unsigned short* __restrict__ vTb,
           const float* __restrict__ freqs,
           float* __restrict__ Cf) {
    __shared__ unsigned short As[2][16384];        // 2 x 32KB
    __shared__ unsigned short Bs[2][16384];        // 2 x 32KB

    int tid  = threadIdx.x;
    int lane = tid & 63, w = tid >> 6;
    int l15  = lane & 15, quad = lane >> 4;
    int wr = w >> 2, wc = w & 3;
    int row0 = blockIdx.y * 256, col0 = blockIdx.x * 256;
    int slot0 = (quad ^ (lane & 7)) * 8;           // kk=0 chunk slot (elements)
    int slot1 = slot0 ^ 32;                        // kk=1: chunk+4 -> ^32 elems

    const unsigned short* Arow = A  + (size_t)row0 * 2048;
    const unsigned short* Brow = BT + (size_t)col0 * 2048;

    f32x4 acc[8][4];
    #pragma unroll
    for (int i = 0; i < 8; ++i)
        #pragma unroll
        for (int j = 0; j < 4; ++j) acc[i][j] = f32x4{0.f, 0.f, 0.f, 0.f};

    bf16x8 af[4][2];          // current m-half A frags
    bf16x8 bfr[2][2][2];      // both n-halves of B frags, live across phases

    // prologue: tile0 (4 halves) + tile1 (A0,B0,B1); A1(1) staged at iter0-ph0
    STG(Arow, &As[0][0], 0, 0);
    STG(Brow, &Bs[0][0], 0, 0);
    STG(Arow, &As[0][0], 1, 0);
    STG(Brow, &Bs[0][0], 1, 0);
    STG(Arow, &As[1][0], 0, 1);
    STG(Brow, &Bs[1][0], 0, 1);
    STG(Brow, &Bs[1][0], 1, 1);
    GATE6;                    // tile0's 8 loads landed; tile1's 6 in flight
    BAR;

    #pragma unroll 1
    for (int i = 0; i < 15; ++i) {
        int t = 2 * i;
        // ph0
        RD_AF(0, 0); RD_BF(0, 0); STG(Arow, &As[1][0], 1, t + 1);
        BAR; LG0; PHI; MM(0, 0); PLO; BAR;
        // ph1
        RD_BF(0, 1); STG(Arow, &As[0][0], 0, t + 2);
        BAR; LG0; PHI; MM(0, 1); PLO; BAR;
        // ph2
        RD_AF(0, 1); STG(Brow, &Bs[0][0], 0, t + 2);
        BAR; LG0; PHI; MM(1, 0); PLO; BAR;
        // ph3
        STG(Brow, &Bs[0][0], 1, t + 2);
        BAR; LG0; PHI; MM(1, 1); PLO; GATE6; BAR;
        // ph4
        RD_AF(1, 0); RD_BF(1, 0); STG(Arow, &As[0][0], 1, t + 2);
        BAR; LG0; PHI; MM(0, 0); PLO; BAR;
        // ph5
        RD_BF(1, 1); STG(Arow, &As[1][0], 0, t + 3);
        BAR; LG0; PHI; MM(0, 1); PLO; BAR;
        // ph6
        RD_AF(1, 1); STG(Brow, &Bs[1][0], 0, t + 3);
        BAR; LG0; PHI; MM(1, 0); PLO; BAR;
        // ph7
        STG(Brow, &Bs[1][0], 1, t + 3);
        BAR; LG0; PHI; MM(1, 1); PLO; GATE6; BAR;
    }
    // final iteration: t = 30 (stage only A1(31); drain at ph3)
    RD_AF(0, 0); RD_BF(0, 0); STG(Arow, &As[1][0], 1, 31);
    BAR; LG0; PHI; MM(0, 0); PLO; BAR;
    RD_BF(0, 1);
    BAR; LG0; PHI; MM(0, 1); PLO; BAR;
    RD_AF(0, 1);
    BAR; LG0; PHI; MM(1, 0); PLO; BAR;
    BAR; LG0; PHI; MM(1, 1); PLO; GATE0; BAR;
    RD_AF(1, 0); RD_BF(1, 0);
    BAR; LG0; PHI; MM(0, 0); PLO; BAR;
    RD_BF(1, 1);
    BAR; LG0; PHI; MM(0, 1); PLO; BAR;
    RD_AF(1, 1);
    BAR; LG0; PHI; MM(1, 0); PLO; BAR;
    LG0; PHI; MM(1, 1); PLO;

    // ---------------- epilogue ----------------
    // C/D 16x16 layout: col = lane&15, row = quad*4 + reg  [m89/m91]
    int q4 = quad * 4;
    if (mode == 0) {
        if (col0 < 2560) {                    // Q or K cols: fused RoPE
            #pragma unroll
            for (int mi = 0; mi < 2; ++mi)
            #pragma unroll
            for (int f = 0; f < 4; ++f) {
                int mb = row0 + mi*128 + wr*64 + f*16 + q4;
                #pragma unroll
                for (int ni = 0; ni < 2; ++ni)
                #pragma unroll
                for (int g = 0; g < 2; ++g) {
                    int colb = col0 + ni*128 + wc*32 + g*16 + l15;
                    int dd = (colb & 127) & ~1;
                    bool odd = colb & 1;
                    #pragma unroll
                    for (int rr = 0; rr < 4; ++rr) {
                        int m = mb + rr;
                        int s = m & 2047;
                        float v  = acc[mi*4 + f][ni*2 + g][rr];
                        float pv = __shfl_xor(v, 1);
                        float cs = freqs[s*128 + dd];
                        float sn = freqs[s*128 + dd + 1];
                        float o  = odd ? (pv*sn + v*cs) : (v*cs - pv*sn);
                        qkvb[(size_t)m * NQKV + colb] = f2b(o);
                    }
                }
            }
        } else {                              // V cols: transposed store
            #pragma unroll
            for (int mi = 0; mi < 2; ++mi)
            #pragma unroll
            for (int f = 0; f < 4; ++f) {
                int mb = row0 + mi*128 + wr*64 + f*16 + q4;
                int s0 = mb & 2047;
                #pragma unroll
                for (int ni = 0; ni < 2; ++ni)
                #pragma unroll
                for (int g = 0; g < 2; ++g) {
                    int colb = col0 + ni*128 + wc*32 + g*16 + l15;
                    int vrow = (row0 >> 11) * 512 + (colb - 2560);
                    ushort4 ov;
                    ov.x = f2b(acc[mi*4 + f][ni*2 + g][0]);
                    ov.y = f2b(acc[mi*4 + f][ni*2 + g][1]);
                    ov.z = f2b(acc[mi*4 + f][ni*2 + g][2]);
                    ov.w = f2b(acc[mi*4 + f][ni*2 + g][3]);
                    *(ushort4*)(vTb + (size_t)vrow * 2048 + s0) = ov;
                }
            }
        }
    } else {                                  // output projection: f32 C
        #pragma unroll
        for (int mi = 0; mi < 2; ++mi)
        #pragma unroll
        for (int f = 0; f < 4; ++f) {
            int mb = row0 + mi*128 + wr*64 + f*16 + q4;
            #pragma unroll
            for (int ni = 0; ni < 2; ++ni)
            #pragma unroll
            for (int g = 0; g < 2; ++g) {
                int colb = col0 + ni*128 + wc*32 + g*16 + l15;
                #pragma unroll
                for (int rr = 0; rr < 4; ++rr)
                    Cf[(size_t)(mb + rr) * 2048 + colb] = acc[mi*4 + f][ni*2 + g][rr];
            }
        }
    }
}

// ---------- GQA-fused MFMA flash attention (unchanged) ---------------------
__global__ __launch_bounds__(512)
void attn_mfma(const unsigned short* __restrict__ qkv,
               const unsigned short* __restrict__ vT,
               unsigned short* __restrict__ ao,
               unsigned short* __restrict__ wsP,
               float2* __restrict__ wsML) {
    __shared__ unsigned short Ks[64 * 128];   // 16KB, XOR-swizzled
    __shared__ unsigned short Vt[128 * 64];   // 16KB, XOR-swizzled

    int tid  = threadIdx.x;
    int lane = tid & 63, w = tid >> 6;        // w in 0..7
    int quad = lane >> 4, l15 = lane & 15;
    int hw = w >> 1, qhalf = w & 1;
    int bx = blockIdx.x, hk = blockIdx.y, b = blockIdx.z;
    int h = hk * 4 + hw;

    int qt, c;
    if (bx < 12)      { qt = 31 - bx / 3;        c = bx % 3; }
    else if (bx < 40) { qt = 27 - (bx - 12) / 2; c = (bx - 12) & 1; }
    else              { qt = 53 - bx;            c = 0; }
    int nt = qt + 1;
    int nch = (qt >= 28) ? 3 : (qt >= 14 ? 2 : 1);
    int kt_begin = c * 14;
    int kt_end = (nt < (c + 1) * 14) ? nt : (c + 1) * 14;
    bool lastc = (c == nch - 1);
    int q0 = qt * 64;
    const float scale = 0.08838834764831845f;   // 1/sqrt(128)

    bf16x8 aq[2][4];
    #pragma unroll
    for (int qf = 0; qf < 2; qf++) {
        const unsigned short* qrow =
            qkv + (size_t)(b*2048 + q0 + qhalf*32 + qf*16 + l15) * NQKV + h*128;
        #pragma unroll
        for (int k4 = 0; k4 < 4; k4++)
            aq[qf][k4] = *(const bf16x8*)(qrow + k4*32 + quad*8);
    }

    int koff[4][4];
    #pragma unroll
    for (int j = 0; j < 4; j++) {
        int row = ((j >> 1) * 32) + ((l15 >> 2) * 8) + ((j & 1) * 4) + (l15 & 3);
        #pragma unroll
        for (int k4 = 0; k4 < 4; k4++) {
            int slot = (k4 * 4 + quad) ^ (row & 15);
            koff[j][k4] = (row * 16 + slot) * 8;
        }
    }
    int vbase0 = (l15 * 8 + (quad ^ (l15 & 7))) * 8;
    int vbase1 = (l15 * 8 + ((4 + quad) ^ (l15 & 7))) * 8;

    const unsigned short* kb0 = qkv + (size_t)(b*2048) * NQKV + 2048 + hk*128;
    const unsigned short* vb0 = vT + (size_t)(b*512 + hk*128) * 2048;

    auto stage_k = [&](int kt) {
        #pragma unroll
        for (int it = 0; it < 2; it++) {
            int s = w * 128 + it * 64 + lane;
            int r = s >> 4, qp = s & 15;
            int q = qp ^ (r & 15);
            __builtin_amdgcn_global_load_lds(
                (gas_p)(kb0 + (size_t)(kt*64 + r) * NQKV + q * 8),
                (las_p)((char*)&Ks[0] + (w * 128 + it * 64) * 16),
                16, 0, 0);
        }
    };
    auto stage_v = [&](int kt) {
        #pragma unroll
        for (int it = 0; it < 2; it++) {
            int s = w * 128 + it * 64 + lane;
            int r = s >> 3, qp = s & 7;
            int q = qp ^ (r & 7);
            __builtin_amdgcn_global_load_lds(
                (gas_p)(vb0 + (size_t)r * 2048 + kt*64 + q * 8),
                (las_p)((char*)&Vt[0] + (w * 128 + it * 64) * 16),
                16, 0, 0);
        }
    };

    f32x4 o_acc[2][8];
    const f32x4 zf = {0.f, 0.f, 0.f, 0.f};
    #pragma unroll
    for (int qf = 0; qf < 2; qf++)
        #pragma unroll
        for (int jn = 0; jn < 8; jn++) o_acc[qf][jn] = zf;
    float m_i[2] = {-1e30f, -1e30f}, l_i[2] = {0.f, 0.f};
    int qglob[2] = {q0 + qhalf*32 + l15, q0 + qhalf*32 + 16 + l15};

    stage_k(kt_begin);
    for (int kt = kt_begin; kt < kt_end; kt++) {
        __syncthreads();             // A: K(kt) landed; V buffer free
        stage_v(kt);                 // async during QK+softmax

        f32x4 s_acc[2][4];
        #pragma unroll
        for (int j = 0; j < 4; j++) {
            s_acc[0][j] = zf; s_acc[1][j] = zf;
            #pragma unroll
            for (int k4 = 0; k4 < 4; k4++) {
                bf16x8 ak = *(const bf16x8*)&Ks[koff[j][k4]];
                s_acc[0][j] = __builtin_amdgcn_mfma_f32_16x16x32_bf16(ak, aq[0][k4], s_acc[0][j], 0, 0, 0);
                s_acc[1][j] = __builtin_amdgcn_mfma_f32_16x16x32_bf16(ak, aq[1][k4], s_acc[1][j], 0, 0, 0);
            }
        }

        bf16x8 pp[2][2];
        #pragma unroll
        for (int qf = 0; qf < 2; qf++) {
            float sv[4][4];
            #pragma unroll
            for (int j = 0; j < 4; j++)
                #pragma unroll
                for (int r = 0; r < 4; r++)
                    sv[j][r] = s_acc[qf][j][r] * scale;
            if (kt == qt) {
                #pragma unroll
                for (int j = 0; j < 4; j++)
                    #pragma unroll
                    for (int r = 0; r < 4; r++) {
                        int sloc = ((j >> 1) * 32) + quad*8 + ((j & 1) * 4) + r;
                        if (kt*64 + sloc > qglob[qf]) sv[j][r] = -1e30f;
                    }
            }
            float mx = sv[0][0];
            #pragma unroll
            for (int j = 0; j < 4; j++)
                #pragma unroll
                for (int r = 0; r < 4; r++) mx = fmaxf(mx, sv[j][r]);
            mx = fmaxf(mx, __shfl_xor(mx, 16));
            mx = fmaxf(mx, __shfl_xor(mx, 32));
            float mnew = fmaxf(m_i[qf], mx);
            float alpha = __expf(m_i[qf] - mnew);
            float rs = 0.f;
            float p[4][4];
            #pragma unroll
            for (int j = 0; j < 4; j++)
                #pragma unroll
                for (int r = 0; r < 4; r++) {
                    p[j][r] = __expf(sv[j][r] - mnew);
                    rs += p[j][r];
                }
            l_i[qf] = l_i[qf] * alpha + rs;
            m_i[qf] = mnew;
            #pragma unroll
            for (int jn = 0; jn < 8; jn++)
                #pragma unroll
                for (int r = 0; r < 4; r++) o_acc[qf][jn][r] *= alpha;
            #pragma unroll
            for (int r = 0; r < 4; r++) {
                pp[qf][0][r]     = (short)f2b(p[0][r]);
                pp[qf][0][r + 4] = (short)f2b(p[1][r]);
                pp[qf][1][r]     = (short)f2b(p[2][r]);
                pp[qf][1][r + 4] = (short)f2b(p[3][r]);
            }
        }

        __syncthreads();             // B: V(kt) landed; K buffer free
        if (kt + 1 < kt_end) stage_k(kt + 1);

        #pragma unroll
        for (int jn = 0; jn < 8; jn++) {
            bf16x8 av0 = *(const bf16x8*)&Vt[jn*1024 + vbase0];
            bf16x8 av1 = *(const bf16x8*)&Vt[jn*1024 + vbase1];
            o_acc[0][jn] = __builtin_amdgcn_mfma_f32_16x16x32_bf16(av0, pp[0][0], o_acc[0][jn], 0, 0, 0);
            o_acc[0][jn] = __builtin_amdgcn_mfma_f32_16x16x32_bf16(av1, pp[0][1], o_acc[0][jn], 0, 0, 0);
            o_acc[1][jn] = __builtin_amdgcn_mfma_f32_16x16x32_bf16(av0, pp[1][0], o_acc[1][jn], 0, 0, 0);
            o_acc[1][jn] = __builtin_amdgcn_mfma_f32_16x16x32_bf16(av1, pp[1][1], o_acc[1][jn], 0, 0, 0);
        }
    }

    int pi = 0, mi = 0;
    if (qt >= 14) {
        if (qt < 28) { mi = (qt - 14) * 2 + c;       pi = qt - 14; }
        else         { mi = 28 + (qt - 28) * 3 + c;  pi = 14 + (qt - 28) * 2 + c; }
    }
    #pragma unroll
    for (int qf = 0; qf < 2; qf++) {
        float lt = l_i[qf];
        lt += __shfl_xor(lt, 16);
        lt += __shfl_xor(lt, 32);
        float inv = 1.f / lt;
        int q_local = qhalf * 32 + qf * 16 + l15;
        unsigned short* dst;
        if (lastc)
            dst = ao + (size_t)(b*2048 + q0 + q_local) * 2048 + h*128;
        else
            dst = wsP + (size_t)(((pi * 8 + hk * 2 + b) * 4 + hw) * 64 + q_local) * 128;
        #pragma unroll
        for (int jn = 0; jn < 8; jn++) {
            ushort4 ov;
            ov.x = f2b(o_acc[qf][jn][0] * inv);
            ov.y = f2b(o_acc[qf][jn][1] * inv);
            ov.z = f2b(o_acc[qf][jn][2] * inv);
            ov.w = f2b(o_acc[qf][jn][3] * inv);
            *(ushort4*)(dst + jn*16 + quad*4) = ov;
        }
        if (qt >= 14 && quad == 0)
            wsML[(mi * 8 + hk * 2 + b) * 256 + hw * 64 + q_local]
                = make_float2(m_i[qf], lt);
    }
}

// ---------- merge split-K partials (rows q >= 896, 2-3 chunks) -------------
__global__ __launch_bounds__(256)
void merge_kernel(unsigned short* __restrict__ ao,
                  const unsigned short* __restrict__ wsP,
                  const float2* __restrict__ wsML) {
    int t = blockIdx.x * 256 + threadIdx.x;
    int d = (t & 15) * 8;
    int h = (t >> 4) & 15;
    int rest = t >> 8;                // 0..2303
    int q_off = rest % 1152;
    int b = rest / 1152;
    int q = 896 + q_off;
    int qt = q >> 6, q_local = q & 63;
    int hk = h >> 2, hw = h & 3;
    int nch = (qt >= 28) ? 3 : 2;

    float mv[3], lv[3];
    for (int cc = 0; cc < nch; cc++) {
        int mi = (qt < 28) ? (qt - 14) * 2 + cc : 28 + (qt - 28) * 3 + cc;
        float2 ml = wsML[(mi * 8 + hk * 2 + b) * 256 + hw * 64 + q_local];
        mv[cc] = ml.x; lv[cc] = ml.y;
    }
    float M = mv[0];
    for (int cc = 1; cc < nch; cc++) M = fmaxf(M, mv[cc]);
    float f[3], S = 0.f;
    for (int cc = 0; cc < nch; cc++) { f[cc] = __expf(mv[cc] - M) * lv[cc]; S += f[cc]; }
    float inv = 1.f / S;

    unsigned short* arow = ao + (size_t)(b*2048 + q) * 2048 + h*128 + d;
    float outv[8];
    {
        ushort4 a0 = *(ushort4*)arow, a1 = *(ushort4*)(arow + 4);
        float fl = f[nch-1];
        outv[0] = fl*b2f(a0.x); outv[1] = fl*b2f(a0.y);
        outv[2] = fl*b2f(a0.z); outv[3] = fl*b2f(a0.w);
        outv[4] = fl*b2f(a1.x); outv[5] = fl*b2f(a1.y);
        outv[6] = fl*b2f(a1.z); outv[7] = fl*b2f(a1.w);
    }
    for (int cc = 0; cc < nch - 1; cc++) {
        int pi = (qt < 28) ? (qt - 14) : 14 + (qt - 28) * 2 + cc;
        const unsigned short* prow =
            wsP + (size_t)(((pi * 8 + hk * 2 + b) * 4 + hw) * 64 + q_local) * 128 + d;
        ushort4 p0 = *(const ushort4*)prow, p1 = *(const ushort4*)(prow + 4);
        float fc = f[cc];
        outv[0] += fc*b2f(p0.x); outv[1] += fc*b2f(p0.y);
        outv[2] += fc*b2f(p0.z); outv[3] += fc*b2f(p0.w);
        outv[4] += fc*b2f(p1.x); outv[5] += fc*b2f(p1.y);
        outv[6] += fc*b2f(p1.z); outv[7] += fc*b2f(p1.w);
    }
    ushort4 o0, o1;
    o0.x = f2b(outv[0]*inv); o0.y = f2b(outv[1]*inv);
    o0.z = f2b(outv[2]*inv); o0.w = f2b(outv[3]*inv);
    o1.x = f2b(outv[4]*inv); o1.y = f2b(outv[5]*inv);
    o1.z = f2b(outv[6]*inv); o1.w = f2b(outv[7]*inv);
    *(ushort4*)arow = o0;
    *(ushort4*)(arow + 4) = o1;
}

// ---------- launch ---------------------------------------------------------
extern "C" void kernel_launch(void* const* d_in, const int* in_sizes, int n_in,
                              void* d_out, int out_size, void* d_ws, size_t ws_size,
                              hipStream_t stream) {
    const float* x     = (const float*)d_in[0];
    const float* freqs = (const float*)d_in[1];
    const float* wq    = (const float*)d_in[2];
    const float* wk    = (const float*)d_in[3];
    const float* wv    = (const float*)d_in[4];
    const float* wo    = (const float*)d_in[5];
    float* out = (float*)d_out;

    char* ws = (char*)d_ws;
    unsigned short* xbf    = (unsigned short*)(ws);                  // 16MB
    unsigned short* aobuf  = (unsigned short*)(ws);                  // alias (xbf dead)
    unsigned short* wqkvT  = (unsigned short*)(ws + (16u<<20));      // 12MB
    unsigned short* woT    = (unsigned short*)(ws + (28u<<20));      // 8MB
    unsigned short* qkvbuf = (unsigned short*)(ws + (36u<<20));      // 24MB
    unsigned short* vTbuf  = (unsigned short*)(ws + (60u<<20));      // 4MB
    unsigned short* wsP  = (unsigned short*)(ws + (16u<<20));        // 11MB (aliases wqkvT, dead)
    float2*         wsML = (float2*)(ws + (16u<<20) + 176u*65536u);  // 640KB

    dim3 blk(256);
    convert_x<<<8192, blk, 0, stream>>>(x, xbf);
    convert_w_all<<<dim3(64, 64, 4), blk, 0, stream>>>(wq, wk, wv, wo, wqkvT, woT);
    gemm8<<<dim3(NQKV/256, M_/256), dim3(512), 0, stream>>>(
        xbf, wqkvT, 0, qkvbuf, vTbuf, freqs, nullptr);
    attn_mfma<<<dim3(54, 4, 2), dim3(512), 0, stream>>>(qkvbuf, vTbuf, aobuf, wsP, wsML);
    merge_kernel<<<2304, blk, 0, stream>>>(aobuf, wsP, wsML);
    gemm8<<<dim3(2048/256, M_/256), dim3(512), 0, stream>>>(
        aobuf, woT, 1, nullptr, nullptr, nullptr, out);
}

// Round 2
// 318.165 us; speedup vs baseline: 1.0955x; 1.0955x over previous
//
#include <hip/hip_runtime.h>
#include <hip/hip_bf16.h>

#define B_   2
#define S_   2048
#define HID_ 2048
#define H_   16
#define KVH_ 4
#define D_   128
#define M_   4096
#define NQKV 3072

typedef __attribute__((ext_vector_type(8))) short bf16x8;    // 8 bf16 = 4 VGPR
typedef __attribute__((ext_vector_type(4))) float f32x4;
typedef __attribute__((ext_vector_type(16))) float f32x16;
typedef const __attribute__((address_space(1))) unsigned int* gas_p;
typedef __attribute__((address_space(3))) unsigned int* las_p;

__device__ __forceinline__ unsigned short f2b(float f) {
    __hip_bfloat16 h = __float2bfloat16(f);
    return *reinterpret_cast<unsigned short*>(&h);
}
__device__ __forceinline__ float b2f(unsigned short u) {
    __hip_bfloat16 h;
    *reinterpret_cast<unsigned short*>(&h) = u;
    return __bfloat162float(h);
}

// ---------- convert x: fp32 -> bf16 ----------------------------------------
__global__ __launch_bounds__(256)
void convert_x(const float* __restrict__ x, unsigned short* __restrict__ xb) {
    int i = (blockIdx.x * 256 + threadIdx.x) * 4;
    float4 v = *(const float4*)(x + i);
    ushort4 o;
    o.x = f2b(v.x); o.y = f2b(v.y); o.z = f2b(v.z); o.w = f2b(v.w);
    *(ushort4*)(xb + i) = o;
}

// ---------- all four weight converts in one launch (z selects matrix) ------
__global__ __launch_bounds__(256)
void convert_w_all(const float* __restrict__ wq, const float* __restrict__ wk,
                   const float* __restrict__ wv, const float* __restrict__ wo,
                   unsigned short* __restrict__ wqkvT,
                   unsigned short* __restrict__ woT) {
    __shared__ float tile[32][33];
    int z = blockIdx.z;
    const float* w; int N, nbase; unsigned short* dst;
    if (z == 0)      { w = wq; N = 2048; nbase = 0;    dst = wqkvT; }
    else if (z == 1) { w = wk; N = 512;  nbase = 2048; dst = wqkvT; }
    else if (z == 2) { w = wv; N = 512;  nbase = 2560; dst = wqkvT; }
    else             { w = wo; N = 2048; nbase = 0;    dst = woT; }
    int n0 = blockIdx.x * 32, k0 = blockIdx.y * 32;
    if (n0 >= N) return;
    int tx = threadIdx.x & 31, ty = threadIdx.x >> 5;
    #pragma unroll
    for (int j = 0; j < 4; j++)
        tile[ty + j*8][tx] = w[(size_t)(k0 + ty + j*8) * N + n0 + tx];
    __syncthreads();
    #pragma unroll
    for (int j = 0; j < 4; j++)
        dst[(size_t)(nbase + n0 + ty + j*8) * 2048 + k0 + tx] = f2b(tile[tx][ty + j*8]);
}

// ---------- shared 8-phase machinery ---------------------------------------
#define BAR    asm volatile("s_barrier" ::: "memory")
#define LG0    do { asm volatile("s_waitcnt lgkmcnt(0)" ::: "memory"); \
                    __builtin_amdgcn_sched_barrier(0); } while (0)
#define GATE6  asm volatile("s_waitcnt vmcnt(6)" ::: "memory")
#define GATE0  asm volatile("s_waitcnt vmcnt(0)" ::: "memory")
#define PHI    __builtin_amdgcn_s_setprio(1)
#define PLO    __builtin_amdgcn_s_setprio(0)

// stage one 128-row x 64-col bf16 half-tile (16KB) via global_load_lds w=16,
// inverse-XOR-swizzled global source, linear LDS dest (rule 21)
#define STG(srcrow, ldsbase, half, tile) do {                                   \
    _Pragma("unroll")                                                           \
    for (int it_ = 0; it_ < 2; ++it_) {                                         \
      int p_ = w * 128 + it_ * 64 + lane;                                       \
      int r_ = (half) * 128 + (p_ >> 3);                                        \
      int q8_ = ((p_ & 7) ^ ((p_ >> 3) & 7)) * 8;                               \
      __builtin_amdgcn_global_load_lds(                                         \
          (gas_p)((srcrow) + (size_t)r_ * 2048 + (tile) * 64 + q8_),            \
          (las_p)((char*)(ldsbase) + ((half) * 1024 + w * 128 + it_ * 64) * 16),\
          16, 0, 0);                                                            \
    } } while (0)

// ---------- QKV GEMM: 256x256 8-phase (T1+T2+T3+T4+T5), fused RoPE/vT ------
// 512 thr = 8 waves (2M x 4N), per-wave 128x64 C, 16x16x32 MFMA.
// Schedule verified r1 (passed, bank-conflict 0); this round adds T1 swizzle.
#define RD_AF(bufi, mi) do {                                                    \
    const unsigned short* Ab_ = &As[bufi][0] + (mi) * 8192 + wr * 4096 + l15 * 64; \
    _Pragma("unroll")                                                           \
    for (int f_ = 0; f_ < 4; ++f_) {                                            \
      af[f_][0] = *(const bf16x8*)(Ab_ + f_ * 1024 + slot0);                    \
      af[f_][1] = *(const bf16x8*)(Ab_ + f_ * 1024 + slot1);                    \
    } } while (0)

#define RD_BF(bufi, ni) do {                                                    \
    const unsigned short* Bb_ = &Bs[bufi][0] + (ni) * 8192 + wc * 2048 + l15 * 64; \
    _Pragma("unroll")                                                           \
    for (int g_ = 0; g_ < 2; ++g_) {                                            \
      bfr[ni][g_][0] = *(const bf16x8*)(Bb_ + g_ * 1024 + slot0);               \
      bfr[ni][g_][1] = *(const bf16x8*)(Bb_ + g_ * 1024 + slot1);               \
    } } while (0)

#define MM(mi, ni) do {                                                         \
    _Pragma("unroll")                                                           \
    for (int f_ = 0; f_ < 4; ++f_)                                              \
      _Pragma("unroll")                                                         \
      for (int g_ = 0; g_ < 2; ++g_) {                                          \
        acc[(mi)*4 + f_][(ni)*2 + g_] = __builtin_amdgcn_mfma_f32_16x16x32_bf16(\
            af[f_][0], bfr[ni][g_][0], acc[(mi)*4 + f_][(ni)*2 + g_], 0, 0, 0); \
        acc[(mi)*4 + f_][(ni)*2 + g_] = __builtin_amdgcn_mfma_f32_16x16x32_bf16(\
            af[f_][1], bfr[ni][g_][1], acc[(mi)*4 + f_][(ni)*2 + g_], 0, 0, 0); \
      } } while (0)

__global__ __launch_bounds__(512)
void gemm8(const unsigned short* __restrict__ A,
           const unsigned short* __restrict__ BT,
           unsigned short* __restrict__ qkvb,
           unsigned short* __restrict__ vTb,
           const float* __restrict__ freqs) {
    __shared__ unsigned short As[2][16384];        // 2 x 32KB
    __shared__ unsigned short Bs[2][16384];        // 2 x 32KB

    int tid  = threadIdx.x;
    int lane = tid & 63, w = tid >> 6;
    int l15  = lane & 15, quad = lane >> 4;
    int wr = w >> 2, wc = w & 3;
    // T1: XCD-chunked bijective swizzle (nwg=192, 192%8==0 -> simple form).
    // Consecutive s share a by (A row-panel) -> per-XCD L2 reuse.
    int bid = blockIdx.y * 12 + blockIdx.x;
    int s_  = (bid & 7) * 24 + (bid >> 3);
    int by  = s_ / 12, bx = s_ % 12;
    int row0 = by * 256, col0 = bx * 256;
    int slot0 = (quad ^ (lane & 7)) * 8;           // kk=0 chunk slot (elements)
    int slot1 = slot0 ^ 32;                        // kk=1: chunk+4 -> ^32 elems

    const unsigned short* Arow = A  + (size_t)row0 * 2048;
    const unsigned short* Brow = BT + (size_t)col0 * 2048;

    f32x4 acc[8][4];
    #pragma unroll
    for (int i = 0; i < 8; ++i)
        #pragma unroll
        for (int j = 0; j < 4; ++j) acc[i][j] = f32x4{0.f, 0.f, 0.f, 0.f};

    bf16x8 af[4][2];          // current m-half A frags
    bf16x8 bfr[2][2][2];      // both n-halves of B frags, live across phases

    // prologue: tile0 (4 halves) + tile1 (A0,B0,B1); A1(1) staged at iter0-ph0
    STG(Arow, &As[0][0], 0, 0);
    STG(Brow, &Bs[0][0], 0, 0);
    STG(Arow, &As[0][0], 1, 0);
    STG(Brow, &Bs[0][0], 1, 0);
    STG(Arow, &As[1][0], 0, 1);
    STG(Brow, &Bs[1][0], 0, 1);
    STG(Brow, &Bs[1][0], 1, 1);
    GATE6;                    // tile0's 8 loads landed; tile1's 6 in flight
    BAR;

    #pragma unroll 1
    for (int i = 0; i < 15; ++i) {
        int t = 2 * i;
        // ph0
        RD_AF(0, 0); RD_BF(0, 0); STG(Arow, &As[1][0], 1, t + 1);
        BAR; LG0; PHI; MM(0, 0); PLO; BAR;
        // ph1
        RD_BF(0, 1); STG(Arow, &As[0][0], 0, t + 2);
        BAR; LG0; PHI; MM(0, 1); PLO; BAR;
        // ph2
        RD_AF(0, 1); STG(Brow, &Bs[0][0], 0, t + 2);
        BAR; LG0; PHI; MM(1, 0); PLO; BAR;
        // ph3
        STG(Brow, &Bs[0][0], 1, t + 2);
        BAR; LG0; PHI; MM(1, 1); PLO; GATE6; BAR;
        // ph4
        RD_AF(1, 0); RD_BF(1, 0); STG(Arow, &As[0][0], 1, t + 2);
        BAR; LG0; PHI; MM(0, 0); PLO; BAR;
        // ph5
        RD_BF(1, 1); STG(Arow, &As[1][0], 0, t + 3);
        BAR; LG0; PHI; MM(0, 1); PLO; BAR;
        // ph6
        RD_AF(1, 1); STG(Brow, &Bs[1][0], 0, t + 3);
        BAR; LG0; PHI; MM(1, 0); PLO; BAR;
        // ph7
        STG(Brow, &Bs[1][0], 1, t + 3);
        BAR; LG0; PHI; MM(1, 1); PLO; GATE6; BAR;
    }
    // final iteration: t = 30 (stage only A1(31); drain at ph3)
    RD_AF(0, 0); RD_BF(0, 0); STG(Arow, &As[1][0], 1, 31);
    BAR; LG0; PHI; MM(0, 0); PLO; BAR;
    RD_BF(0, 1);
    BAR; LG0; PHI; MM(0, 1); PLO; BAR;
    RD_AF(0, 1);
    BAR; LG0; PHI; MM(1, 0); PLO; BAR;
    BAR; LG0; PHI; MM(1, 1); PLO; GATE0; BAR;
    RD_AF(1, 0); RD_BF(1, 0);
    BAR; LG0; PHI; MM(0, 0); PLO; BAR;
    RD_BF(1, 1);
    BAR; LG0; PHI; MM(0, 1); PLO; BAR;
    RD_AF(1, 1);
    BAR; LG0; PHI; MM(1, 0); PLO; BAR;
    LG0; PHI; MM(1, 1); PLO;

    // ---------------- epilogue ----------------
    // C/D 16x16 layout: col = lane&15, row = quad*4 + reg  [m89/m91]
    int q4 = quad * 4;
    if (col0 < 2560) {                    // Q or K cols: fused RoPE
        #pragma unroll
        for (int mi = 0; mi < 2; ++mi)
        #pragma unroll
        for (int f = 0; f < 4; ++f) {
            int mb = row0 + mi*128 + wr*64 + f*16 + q4;
            #pragma unroll
            for (int ni = 0; ni < 2; ++ni)
            #pragma unroll
            for (int g = 0; g < 2; ++g) {
                int colb = col0 + ni*128 + wc*32 + g*16 + l15;
                int dd = (colb & 127) & ~1;
                bool odd = colb & 1;
                #pragma unroll
                for (int rr = 0; rr < 4; ++rr) {
                    int m = mb + rr;
                    int s = m & 2047;
                    float v  = acc[mi*4 + f][ni*2 + g][rr];
                    float pv = __shfl_xor(v, 1);
                    float cs = freqs[s*128 + dd];
                    float sn = freqs[s*128 + dd + 1];
                    float o  = odd ? (pv*sn + v*cs) : (v*cs - pv*sn);
                    qkvb[(size_t)m * NQKV + colb] = f2b(o);
                }
            }
        }
    } else {                              // V cols: transposed store
        #pragma unroll
        for (int mi = 0; mi < 2; ++mi)
        #pragma unroll
        for (int f = 0; f < 4; ++f) {
            int mb = row0 + mi*128 + wr*64 + f*16 + q4;
            int s0 = mb & 2047;
            #pragma unroll
            for (int ni = 0; ni < 2; ++ni)
            #pragma unroll
            for (int g = 0; g < 2; ++g) {
                int colb = col0 + ni*128 + wc*32 + g*16 + l15;
                int vrow = (row0 >> 11) * 512 + (colb - 2560);
                ushort4 ov;
                ov.x = f2b(acc[mi*4 + f][ni*2 + g][0]);
                ov.y = f2b(acc[mi*4 + f][ni*2 + g][1]);
                ov.z = f2b(acc[mi*4 + f][ni*2 + g][2]);
                ov.w = f2b(acc[mi*4 + f][ni*2 + g][3]);
                *(ushort4*)(vTb + (size_t)vrow * 2048 + s0) = ov;
            }
        }
    }
}

// ---------- OUT GEMM: 256x128-tile 8-phase, grid 256 = exact 1 block/CU ----
// 8 waves as 4M x 2N -> per-wave 64x64 (squarest split): 16 b128 reads per
// 32 MFMA per K-tile (128KB/K-tile LDS traffic vs 192KB at 256x256).
// LDS 96KB: A[2][256x64]=2x32K, B[2][128x64]=2x16K.
// Stage units/tile: A0 (rows 0-127), A1 (128-255), B (all 128). 6 units per
// 2 K-tiles over 8 phases; GATE6 at ph3/ph7 (12 outstanding -> oldest 6 =
// next tile's units landed). Region safety: all A reads in ph0 (post-BAR ->
// stage A0@ph1, A1@ph2); B reads end ph1 (-> stage B@ph3).
#define RDA(bufi) do {                                                          \
    const unsigned short* Ab_ = &As[bufi][0] + wr * 4096 + l15 * 64;            \
    _Pragma("unroll")                                                           \
    for (int f_ = 0; f_ < 4; ++f_) {                                            \
      af[f_][0] = *(const bf16x8*)(Ab_ + f_ * 1024 + slot0);                    \
      af[f_][1] = *(const bf16x8*)(Ab_ + f_ * 1024 + slot1);                    \
    } } while (0)

#define RDB(bufi, g) do {                                                       \
    const unsigned short* Bb_ = &Bs[bufi][0] + wc * 4096 + l15 * 64;            \
    bfr[g][0] = *(const bf16x8*)(Bb_ + (g) * 1024 + slot0);                     \
    bfr[g][1] = *(const bf16x8*)(Bb_ + (g) * 1024 + slot1);                     \
    } while (0)

#define MM8(mi, ni) do {                                                        \
    _Pragma("unroll")                                                           \
    for (int f_ = 2*(mi); f_ < 2*(mi)+2; ++f_)                                  \
      _Pragma("unroll")                                                         \
      for (int g_ = 2*(ni); g_ < 2*(ni)+2; ++g_) {                              \
        acc[f_][g_] = __builtin_amdgcn_mfma_f32_16x16x32_bf16(                  \
            af[f_][0], bfr[g_][0], acc[f_][g_], 0, 0, 0);                       \
        acc[f_][g_] = __builtin_amdgcn_mfma_f32_16x16x32_bf16(                  \
            af[f_][1], bfr[g_][1], acc[f_][g_], 0, 0, 0);                       \
      } } while (0)

__global__ __launch_bounds__(512)
void gemm8o(const unsigned short* __restrict__ A,
            const unsigned short* __restrict__ BT,
            float* __restrict__ Cf) {
    __shared__ unsigned short As[2][16384];        // 2 x 32KB (256 x 64)
    __shared__ unsigned short Bs[2][8192];         // 2 x 16KB (128 x 64)

    int tid  = threadIdx.x;
    int lane = tid & 63, w = tid >> 6;
    int l15  = lane & 15, quad = lane >> 4;
    int wr = w >> 1, wc = w & 1;                   // 4M x 2N wave grid
    // T1: nwg=256, chunked -> each XCD owns 2 full by-rows (A-panel reuse)
    int bid = blockIdx.y * 16 + blockIdx.x;
    int s_  = (bid & 7) * 32 + (bid >> 3);
    int by  = s_ >> 4, bx = s_ & 15;
    int row0 = by * 256, col0 = bx * 128;
    int slot0 = (quad ^ (lane & 7)) * 8;
    int slot1 = slot0 ^ 32;

    const unsigned short* Arow = A  + (size_t)row0 * 2048;
    const unsigned short* Brow = BT + (size_t)col0 * 2048;

    f32x4 acc[4][4];
    #pragma unroll
    for (int i = 0; i < 4; ++i)
        #pragma unroll
        for (int j = 0; j < 4; ++j) acc[i][j] = f32x4{0.f, 0.f, 0.f, 0.f};

    bf16x8 af[4][2];          // wave's 4 A frags x 2 k-chunks
    bf16x8 bfr[4][2];         // wave's 4 B frags x 2 k-chunks

    // prologue: full tiles 0 (buf0) and 1 (buf1), 6 units = 12 loads
    STG(Arow, &As[0][0], 0, 0);
    STG(Arow, &As[0][0], 1, 0);
    STG(Brow, &Bs[0][0], 0, 0);
    STG(Arow, &As[1][0], 0, 1);
    STG(Arow, &As[1][0], 1, 1);
    STG(Brow, &Bs[1][0], 0, 1);
    GATE6;                    // tile0 landed; tile1's 6 in flight
    BAR;

    #pragma unroll 1
    for (int i = 0; i < 15; ++i) {
        int t = 2 * i;
        // ph0: all A frags + B g0,g1
        RDA(0); RDB(0, 0); RDB(0, 1);
        BAR; LG0; PHI; MM8(0, 0); PLO; BAR;
        // ph1: B g2,g3; stage A0(t+2)
        RDB(0, 2); RDB(0, 3); STG(Arow, &As[0][0], 0, t + 2);
        BAR; LG0; PHI; MM8(0, 1); PLO; BAR;
        // ph2: stage A1(t+2)
        STG(Arow, &As[0][0], 1, t + 2);
        BAR; LG0; PHI; MM8(1, 0); PLO; BAR;
        // ph3: stage B(t+2); gate tile t+1
        STG(Brow, &Bs[0][0], 0, t + 2);
        BAR; LG0; PHI; MM8(1, 1); PLO; GATE6; BAR;
        // ph4 (buf1)
        RDA(1); RDB(1, 0); RDB(1, 1);
        BAR; LG0; PHI; MM8(0, 0); PLO; BAR;
        // ph5
        RDB(1, 2); RDB(1, 3); STG(Arow, &As[1][0], 0, t + 3);
        BAR; LG0; PHI; MM8(0, 1); PLO; BAR;
        // ph6
        STG(Arow, &As[1][0], 1, t + 3);
        BAR; LG0; PHI; MM8(1, 0); PLO; BAR;
        // ph7
        STG(Brow, &Bs[1][0], 0, t + 3);
        BAR; LG0; PHI; MM8(1, 1); PLO; GATE6; BAR;
    }
    // tail: t = 30, 31 (no staging; tile31 gated at ph3)
    RDA(0); RDB(0, 0); RDB(0, 1);
    BAR; LG0; PHI; MM8(0, 0); PLO; BAR;
    RDB(0, 2); RDB(0, 3);
    BAR; LG0; PHI; MM8(0, 1); PLO; BAR;
    BAR; LG0; PHI; MM8(1, 0); PLO; BAR;
    BAR; LG0; PHI; MM8(1, 1); PLO; GATE0; BAR;
    RDA(1); RDB(1, 0); RDB(1, 1);
    BAR; LG0; PHI; MM8(0, 0); PLO; BAR;
    RDB(1, 2); RDB(1, 3);
    BAR; LG0; PHI; MM8(0, 1); PLO; BAR;
    BAR; LG0; PHI; MM8(1, 0); PLO; BAR;
    LG0; PHI; MM8(1, 1); PLO;

    // epilogue: f32 C, layout col=l15, row=quad*4+rr
    int q4 = quad * 4;
    #pragma unroll
    for (int f = 0; f < 4; ++f) {
        int mb = row0 + wr*64 + f*16 + q4;
        #pragma unroll
        for (int g = 0; g < 4; ++g) {
            int colb = col0 + wc*64 + g*16 + l15;
            #pragma unroll
            for (int rr = 0; rr < 4; ++rr)
                Cf[(size_t)(mb + rr) * 2048 + colb] = acc[f][g][rr];
        }
    }
}

// ---------- GQA-fused MFMA flash attention (unchanged) ---------------------
__global__ __launch_bounds__(512)
void attn_mfma(const unsigned short* __restrict__ qkv,
               const unsigned short* __restrict__ vT,
               unsigned short* __restrict__ ao,
               unsigned short* __restrict__ wsP,
               float2* __restrict__ wsML) {
    __shared__ unsigned short Ks[64 * 128];   // 16KB, XOR-swizzled
    __shared__ unsigned short Vt[128 * 64];   // 16KB, XOR-swizzled

    int tid  = threadIdx.x;
    int lane = tid & 63, w = tid >> 6;        // w in 0..7
    int quad = lane >> 4, l15 = lane & 15;
    int hw = w >> 1, qhalf = w & 1;
    int bx = blockIdx.x, hk = blockIdx.y, b = blockIdx.z;
    int h = hk * 4 + hw;

    int qt, c;
    if (bx < 12)      { qt = 31 - bx / 3;        c = bx % 3; }
    else if (bx < 40) { qt = 27 - (bx - 12) / 2; c = (bx - 12) & 1; }
    else              { qt = 53 - bx;            c = 0; }
    int nt = qt + 1;
    int nch = (qt >= 28) ? 3 : (qt >= 14 ? 2 : 1);
    int kt_begin = c * 14;
    int kt_end = (nt < (c + 1) * 14) ? nt : (c + 1) * 14;
    bool lastc = (c == nch - 1);
    int q0 = qt * 64;
    const float scale = 0.08838834764831845f;   // 1/sqrt(128)

    bf16x8 aq[2][4];
    #pragma unroll
    for (int qf = 0; qf < 2; qf++) {
        const unsigned short* qrow =
            qkv + (size_t)(b*2048 + q0 + qhalf*32 + qf*16 + l15) * NQKV + h*128;
        #pragma unroll
        for (int k4 = 0; k4 < 4; k4++)
            aq[qf][k4] = *(const bf16x8*)(qrow + k4*32 + quad*8);
    }

    int koff[4][4];
    #pragma unroll
    for (int j = 0; j < 4; j++) {
        int row = ((j >> 1) * 32) + ((l15 >> 2) * 8) + ((j & 1) * 4) + (l15 & 3);
        #pragma unroll
        for (int k4 = 0; k4 < 4; k4++) {
            int slot = (k4 * 4 + quad) ^ (row & 15);
            koff[j][k4] = (row * 16 + slot) * 8;
        }
    }
    int vbase0 = (l15 * 8 + (quad ^ (l15 & 7))) * 8;
    int vbase1 = (l15 * 8 + ((4 + quad) ^ (l15 & 7))) * 8;

    const unsigned short* kb0 = qkv + (size_t)(b*2048) * NQKV + 2048 + hk*128;
    const unsigned short* vb0 = vT + (size_t)(b*512 + hk*128) * 2048;

    auto stage_k = [&](int kt) {
        #pragma unroll
        for (int it = 0; it < 2; it++) {
            int s = w * 128 + it * 64 + lane;
            int r = s >> 4, qp = s & 15;
            int q = qp ^ (r & 15);
            __builtin_amdgcn_global_load_lds(
                (gas_p)(kb0 + (size_t)(kt*64 + r) * NQKV + q * 8),
                (las_p)((char*)&Ks[0] + (w * 128 + it * 64) * 16),
                16, 0, 0);
        }
    };
    auto stage_v = [&](int kt) {
        #pragma unroll
        for (int it = 0; it < 2; it++) {
            int s = w * 128 + it * 64 + lane;
            int r = s >> 3, qp = s & 7;
            int q = qp ^ (r & 7);
            __builtin_amdgcn_global_load_lds(
                (gas_p)(vb0 + (size_t)r * 2048 + kt*64 + q * 8),
                (las_p)((char*)&Vt[0] + (w * 128 + it * 64) * 16),
                16, 0, 0);
        }
    };

    f32x4 o_acc[2][8];
    const f32x4 zf = {0.f, 0.f, 0.f, 0.f};
    #pragma unroll
    for (int qf = 0; qf < 2; qf++)
        #pragma unroll
        for (int jn = 0; jn < 8; jn++) o_acc[qf][jn] = zf;
    float m_i[2] = {-1e30f, -1e30f}, l_i[2] = {0.f, 0.f};
    int qglob[2] = {q0 + qhalf*32 + l15, q0 + qhalf*32 + 16 + l15};

    stage_k(kt_begin);
    for (int kt = kt_begin; kt < kt_end; kt++) {
        __syncthreads();             // A: K(kt) landed; V buffer free
        stage_v(kt);                 // async during QK+softmax

        f32x4 s_acc[2][4];
        #pragma unroll
        for (int j = 0; j < 4; j++) {
            s_acc[0][j] = zf; s_acc[1][j] = zf;
            #pragma unroll
            for (int k4 = 0; k4 < 4; k4++) {
                bf16x8 ak = *(const bf16x8*)&Ks[koff[j][k4]];
                s_acc[0][j] = __builtin_amdgcn_mfma_f32_16x16x32_bf16(ak, aq[0][k4], s_acc[0][j], 0, 0, 0);
                s_acc[1][j] = __builtin_amdgcn_mfma_f32_16x16x32_bf16(ak, aq[1][k4], s_acc[1][j], 0, 0, 0);
            }
        }

        bf16x8 pp[2][2];
        #pragma unroll
        for (int qf = 0; qf < 2; qf++) {
            float sv[4][4];
            #pragma unroll
            for (int j = 0; j < 4; j++)
                #pragma unroll
                for (int r = 0; r < 4; r++)
                    sv[j][r] = s_acc[qf][j][r] * scale;
            if (kt == qt) {
                #pragma unroll
                for (int j = 0; j < 4; j++)
                    #pragma unroll
                    for (int r = 0; r < 4; r++) {
                        int sloc = ((j >> 1) * 32) + quad*8 + ((j & 1) * 4) + r;
                        if (kt*64 + sloc > qglob[qf]) sv[j][r] = -1e30f;
                    }
            }
            float mx = sv[0][0];
            #pragma unroll
            for (int j = 0; j < 4; j++)
                #pragma unroll
                for (int r = 0; r < 4; r++) mx = fmaxf(mx, sv[j][r]);
            mx = fmaxf(mx, __shfl_xor(mx, 16));
            mx = fmaxf(mx, __shfl_xor(mx, 32));
            float mnew = fmaxf(m_i[qf], mx);
            float alpha = __expf(m_i[qf] - mnew);
            float rs = 0.f;
            float p[4][4];
            #pragma unroll
            for (int j = 0; j < 4; j++)
                #pragma unroll
                for (int r = 0; r < 4; r++) {
                    p[j][r] = __expf(sv[j][r] - mnew);
                    rs += p[j][r];
                }
            l_i[qf] = l_i[qf] * alpha + rs;
            m_i[qf] = mnew;
            #pragma unroll
            for (int jn = 0; jn < 8; jn++)
                #pragma unroll
                for (int r = 0; r < 4; r++) o_acc[qf][jn][r] *= alpha;
            #pragma unroll
            for (int r = 0; r < 4; r++) {
                pp[qf][0][r]     = (short)f2b(p[0][r]);
                pp[qf][0][r + 4] = (short)f2b(p[1][r]);
                pp[qf][1][r]     = (short)f2b(p[2][r]);
                pp[qf][1][r + 4] = (short)f2b(p[3][r]);
            }
        }

        __syncthreads();             // B: V(kt) landed; K buffer free
        if (kt + 1 < kt_end) stage_k(kt + 1);

        #pragma unroll
        for (int jn = 0; jn < 8; jn++) {
            bf16x8 av0 = *(const bf16x8*)&Vt[jn*1024 + vbase0];
            bf16x8 av1 = *(const bf16x8*)&Vt[jn*1024 + vbase1];
            o_acc[0][jn] = __builtin_amdgcn_mfma_f32_16x16x32_bf16(av0, pp[0][0], o_acc[0][jn], 0, 0, 0);
            o_acc[0][jn] = __builtin_amdgcn_mfma_f32_16x16x32_bf16(av1, pp[0][1], o_acc[0][jn], 0, 0, 0);
            o_acc[1][jn] = __builtin_amdgcn_mfma_f32_16x16x32_bf16(av0, pp[1][0], o_acc[1][jn], 0, 0, 0);
            o_acc[1][jn] = __builtin_amdgcn_mfma_f32_16x16x32_bf16(av1, pp[1][1], o_acc[1][jn], 0, 0, 0);
        }
    }

    int pi = 0, mi = 0;
    if (qt >= 14) {
        if (qt < 28) { mi = (qt - 14) * 2 + c;       pi = qt - 14; }
        else         { mi = 28 + (qt - 28) * 3 + c;  pi = 14 + (qt - 28) * 2 + c; }
    }
    #pragma unroll
    for (int qf = 0; qf < 2; qf++) {
        float lt = l_i[qf];
        lt += __shfl_xor(lt, 16);
        lt += __shfl_xor(lt, 32);
        float inv = 1.f / lt;
        int q_local = qhalf * 32 + qf * 16 + l15;
        unsigned short* dst;
        if (lastc)
            dst = ao + (size_t)(b*2048 + q0 + q_local) * 2048 + h*128;
        else
            dst = wsP + (size_t)(((pi * 8 + hk * 2 + b) * 4 + hw) * 64 + q_local) * 128;
        #pragma unroll
        for (int jn = 0; jn < 8; jn++) {
            ushort4 ov;
            ov.x = f2b(o_acc[qf][jn][0] * inv);
            ov.y = f2b(o_acc[qf][jn][1] * inv);
            ov.z = f2b(o_acc[qf][jn][2] * inv);
            ov.w = f2b(o_acc[qf][jn][3] * inv);
            *(ushort4*)(dst + jn*16 + quad*4) = ov;
        }
        if (qt >= 14 && quad == 0)
            wsML[(mi * 8 + hk * 2 + b) * 256 + hw * 64 + q_local]
                = make_float2(m_i[qf], lt);
    }
}

// ---------- merge split-K partials (rows q >= 896, 2-3 chunks) -------------
__global__ __launch_bounds__(256)
void merge_kernel(unsigned short* __restrict__ ao,
                  const unsigned short* __restrict__ wsP,
                  const float2* __restrict__ wsML) {
    int t = blockIdx.x * 256 + threadIdx.x;
    int d = (t & 15) * 8;
    int h = (t >> 4) & 15;
    int rest = t >> 8;                // 0..2303
    int q_off = rest % 1152;
    int b = rest / 1152;
    int q = 896 + q_off;
    int qt = q >> 6, q_local = q & 63;
    int hk = h >> 2, hw = h & 3;
    int nch = (qt >= 28) ? 3 : 2;

    float mv[3], lv[3];
    for (int cc = 0; cc < nch; cc++) {
        int mi = (qt < 28) ? (qt - 14) * 2 + cc : 28 + (qt - 28) * 3 + cc;
        float2 ml = wsML[(mi * 8 + hk * 2 + b) * 256 + hw * 64 + q_local];
        mv[cc] = ml.x; lv[cc] = ml.y;
    }
    float M = mv[0];
    for (int cc = 1; cc < nch; cc++) M = fmaxf(M, mv[cc]);
    float f[3], S = 0.f;
    for (int cc = 0; cc < nch; cc++) { f[cc] = __expf(mv[cc] - M) * lv[cc]; S += f[cc]; }
    float inv = 1.f / S;

    unsigned short* arow = ao + (size_t)(b*2048 + q) * 2048 + h*128 + d;
    float outv[8];
    {
        ushort4 a0 = *(ushort4*)arow, a1 = *(ushort4*)(arow + 4);
        float fl = f[nch-1];
        outv[0] = fl*b2f(a0.x); outv[1] = fl*b2f(a0.y);
        outv[2] = fl*b2f(a0.z); outv[3] = fl*b2f(a0.w);
        outv[4] = fl*b2f(a1.x); outv[5] = fl*b2f(a1.y);
        outv[6] = fl*b2f(a1.z); outv[7] = fl*b2f(a1.w);
    }
    for (int cc = 0; cc < nch - 1; cc++) {
        int pi = (qt < 28) ? (qt - 14) : 14 + (qt - 28) * 2 + cc;
        const unsigned short* prow =
            wsP + (size_t)(((pi * 8 + hk * 2 + b) * 4 + hw) * 64 + q_local) * 128 + d;
        ushort4 p0 = *(const ushort4*)prow, p1 = *(const ushort4*)(prow + 4);
        float fc = f[cc];
        outv[0] += fc*b2f(p0.x); outv[1] += fc*b2f(p0.y);
        outv[2] += fc*b2f(p0.z); outv[3] += fc*b2f(p0.w);
        outv[4] += fc*b2f(p1.x); outv[5] += fc*b2f(p1.y);
        outv[6] += fc*b2f(p1.z); outv[7] += fc*b2f(p1.w);
    }
    ushort4 o0, o1;
    o0.x = f2b(outv[0]*inv); o0.y = f2b(outv[1]*inv);
    o0.z = f2b(outv[2]*inv); o0.w = f2b(outv[3]*inv);
    o1.x = f2b(outv[4]*inv); o1.y = f2b(outv[5]*inv);
    o1.z = f2b(outv[6]*inv); o1.w = f2b(outv[7]*inv);
    *(ushort4*)arow = o0;
    *(ushort4*)(arow + 4) = o1;
}

// ---------- launch ---------------------------------------------------------
extern "C" void kernel_launch(void* const* d_in, const int* in_sizes, int n_in,
                              void* d_out, int out_size, void* d_ws, size_t ws_size,
                              hipStream_t stream) {
    const float* x     = (const float*)d_in[0];
    const float* freqs = (const float*)d_in[1];
    const float* wq    = (const float*)d_in[2];
    const float* wk    = (const float*)d_in[3];
    const float* wv    = (const float*)d_in[4];
    const float* wo    = (const float*)d_in[5];
    float* out = (float*)d_out;

    char* ws = (char*)d_ws;
    unsigned short* xbf    = (unsigned short*)(ws);                  // 16MB
    unsigned short* aobuf  = (unsigned short*)(ws);                  // alias (xbf dead)
    unsigned short* wqkvT  = (unsigned short*)(ws + (16u<<20));      // 12MB
    unsigned short* woT    = (unsigned short*)(ws + (28u<<20));      // 8MB
    unsigned short* qkvbuf = (unsigned short*)(ws + (36u<<20));      // 24MB
    unsigned short* vTbuf  = (unsigned short*)(ws + (60u<<20));      // 4MB
    unsigned short* wsP  = (unsigned short*)(ws + (16u<<20));        // 11MB (aliases wqkvT, dead)
    float2*         wsML = (float2*)(ws + (16u<<20) + 176u*65536u);  // 640KB

    dim3 blk(256);
    convert_x<<<8192, blk, 0, stream>>>(x, xbf);
    convert_w_all<<<dim3(64, 64, 4), blk, 0, stream>>>(wq, wk, wv, wo, wqkvT, woT);
    gemm8<<<dim3(NQKV/256, M_/256), dim3(512), 0, stream>>>(
        xbf, wqkvT, qkvbuf, vTbuf, freqs);
    attn_mfma<<<dim3(54, 4, 2), dim3(512), 0, stream>>>(qkvbuf, vTbuf, aobuf, wsP, wsML);
    merge_kernel<<<2304, blk, 0, stream>>>(aobuf, wsP, wsML);
    gemm8o<<<dim3(2048/128, M_/256), dim3(512), 0, stream>>>(aobuf, woT, out);
}